// Round 11
// baseline (602.788 us; speedup 1.0000x reference)
//
#include <hip/hip_runtime.h>
#include <hip/hip_bf16.h>
#include <cstdint>
#include <cstddef>

#define D 512
#define NHEAD 8
#define LMAX 512
#define NGIN 3

typedef unsigned short u16;
typedef unsigned long long u64;
typedef __attribute__((ext_vector_type(8))) short short8;
typedef __attribute__((ext_vector_type(8))) unsigned short ushort8;
typedef __attribute__((ext_vector_type(4))) unsigned short us4;
typedef __attribute__((ext_vector_type(4))) float f32x4;

static __device__ inline u16 f2bf(float f){
    union { float f; uint32_t u; } c; c.f = f;
    uint32_t r = (c.u + 0x7fffu + ((c.u >> 16) & 1u)) >> 16;
    return (u16)r;
}
static __device__ inline u16 tbf(float f){
    union { float f; uint32_t u; } c; c.f = f;
    return (u16)(c.u >> 16);
}
static __device__ inline float bf2f(u16 h){
    union { uint32_t u; float f; } c; c.u = ((uint32_t)h) << 16; return c.f;
}

#define GLOAD_LDS16(SRC, DST) \
    __builtin_amdgcn_global_load_lds( \
        (const __attribute__((address_space(1))) void*)(SRC), \
        (__attribute__((address_space(3))) void*)(DST), 16, 0, 0)

// ---------------- dtype probe + normalization ----------------
__global__ void probe_kernel(const int* __restrict__ ptr_raw,
                             const unsigned char* __restrict__ mask_raw,
                             int* __restrict__ flags){
    if (threadIdx.x == 0){
        flags[0] = (ptr_raw[1] == 0) ? 1 : 0;
        int cntOdd = 0, cnt4 = 0;
        for (int i = 1; i < 2048; i += 2) cntOdd += (mask_raw[i] != 0);
        for (int i = 4; i < 2048; i += 8) cnt4   += (mask_raw[i] != 0);
        flags[1] = (cntOdd > 64) ? 1 : ((cnt4 > 16) ? 4 : 8);
    }
}

__global__ void conv_int_kernel(const int* __restrict__ raw, int* __restrict__ outp,
                                const int* __restrict__ flags, int n){
    int i = blockIdx.x*256 + threadIdx.x;
    if (i < n) outp[i] = flags[0] ? raw[2*i] : raw[i];
}

__global__ void maskbits_kernel(const unsigned char* __restrict__ raw,
                                u64* __restrict__ outp,
                                const int* __restrict__ flags, int total){
    int idx = blockIdx.x*256 + threadIdx.x;
    if (idx >= total) return;
    int w = flags[1];
    size_t ebase = (size_t)(idx >> 3) * 512 + (size_t)(idx & 7) * 64;
    u64 bits = 0;
    if (w == 1){
        const u64* p8 = (const u64*)(raw + ebase);
        #pragma unroll
        for (int g = 0; g < 8; g++){
            u64 v = p8[g];
            #pragma unroll
            for (int by = 0; by < 8; by++)
                if ((v >> (by*8)) & 0xffull) bits |= 1ull << (g*8 + by);
        }
    } else {
        for (int j = 0; j < 64; j++)
            if (raw[(ebase + j) * (size_t)w]) bits |= 1ull << j;
    }
    outp[idx] = bits;
}

// ---------------- CSR inversion ----------------
__global__ void count_kernel(const int* __restrict__ ei, int* __restrict__ deg, int E, int N){
    int e = blockIdx.x*256 + threadIdx.x;
    if (e < E){
        int d = ei[E + e];
        if ((unsigned)d < (unsigned)N) atomicAdd(&deg[d], 1);
    }
}

__global__ void scan_kernel(const int* __restrict__ deg, int* __restrict__ offs, int n){
    __shared__ int wsum[16];
    __shared__ int carry_s;
    int tid = threadIdx.x, lane = tid & 63, wv = tid >> 6;
    if (tid == 0){ carry_s = 0; offs[0] = 0; }
    __syncthreads();
    int nChunks = (n + 1023) / 1024;
    for (int ch = 0; ch < nChunks; ch++){
        int i = ch*1024 + tid;
        int val = (i < n) ? deg[i] : 0;
        int s = val;
        #pragma unroll
        for (int off = 1; off < 64; off <<= 1){
            int t = __shfl_up(s, off);
            if (lane >= off) s += t;
        }
        if (lane == 63) wsum[wv] = s;
        __syncthreads();
        if (wv == 0){
            int t = (lane < 16) ? wsum[lane] : 0;
            #pragma unroll
            for (int off = 1; off < 16; off <<= 1){
                int u = __shfl_up(t, off);
                if (lane >= off) t += u;
            }
            if (lane < 16) wsum[lane] = t;
        }
        __syncthreads();
        int wbase = wv ? wsum[wv-1] : 0;
        if (i < n) offs[i+1] = carry_s + wbase + s;
        __syncthreads();
        if (tid == 1023) carry_s += wsum[15];
        __syncthreads();
    }
}

__global__ void fill_kernel(const int* __restrict__ ei, const int* __restrict__ offs,
                            int* __restrict__ cursor, int* __restrict__ in_src, int E, int N){
    int e = blockIdx.x*256 + threadIdx.x;
    if (e < E){
        int d = ei[E + e];
        if ((unsigned)d < (unsigned)N){
            int slot = atomicAdd(&cursor[d], 1);
            in_src[offs[d] + slot] = ei[e];
        }
    }
}

// ---------------- split f32 -> hi/lo bf16 planes ----------------
__global__ void split_kernel(const float* __restrict__ in, u16* __restrict__ hi,
                             u16* __restrict__ lo, int total4){
    int i = blockIdx.x*256 + threadIdx.x;
    if (i >= total4) return;
    float4 v = *(const float4*)(in + (size_t)i*4);
    float fv[4] = {v.x, v.y, v.z, v.w};
    us4 h4, l4;
    #pragma unroll
    for (int j = 0; j < 4; j++){
        u16 hh = tbf(fv[j]);
        h4[j] = hh;
        l4[j] = tbf(fv[j] - bf2f(hh));
    }
    *(us4*)(hi + (size_t)i*4) = h4;
    *(us4*)(lo + (size_t)i*4) = l4;
}

// ---------------- gather ----------------
__global__ __launch_bounds__(256) void gather_kernel(const u16* __restrict__ hh,
        const u16* __restrict__ hl,
        const int* __restrict__ offs, const int* __restrict__ in_src,
        u16* __restrict__ oh, u16* __restrict__ ol, int N){
    int node = blockIdx.x*2 + (threadIdx.x >> 7);
    if (node >= N) return;
    int t = threadIdx.x & 127;
    size_t rb = (size_t)node*D + t*4;
    us4 vh = *(const us4*)(hh + rb);
    us4 vl = *(const us4*)(hl + rb);
    float a[4];
    #pragma unroll
    for (int j = 0; j < 4; j++) a[j] = bf2f(vh[j]) + bf2f(vl[j]);
    int s = offs[node], e = offs[node+1];
    for (int i = s; i < e; i++){
        size_t sb = (size_t)in_src[i]*D + t*4;
        us4 nh = *(const us4*)(hh + sb);
        us4 nl = *(const us4*)(hl + sb);
        #pragma unroll
        for (int j = 0; j < 4; j++) a[j] += bf2f(nh[j]) + bf2f(nl[j]);
    }
    us4 h4, l4;
    #pragma unroll
    for (int j = 0; j < 4; j++){
        u16 hh2 = tbf(a[j]);
        h4[j] = hh2;
        l4[j] = tbf(a[j] - bf2f(hh2));
    }
    *(us4*)(oh + rb) = h4;
    *(us4*)(ol + rb) = l4;
}

// ---------------- fat weight transpose + split convert ----------------
// z: 0=v,1=g1[0],2=g2[0],3=g1[1],4=g2[1],5=g1[2],6=g2[2],7=se,8=out,9=qk(Nout=1024)
__global__ __launch_bounds__(256) void transpose_all(
        const float* __restrict__ v_w, const float* __restrict__ gin_w1,
        const float* __restrict__ gin_w2, const float* __restrict__ se_w,
        const float* __restrict__ out_w, const float* __restrict__ qk_w,
        u16* __restrict__ wtsh, u16* __restrict__ wtsl){
    const size_t SLOT = 262144;
    int z = blockIdx.z;
    int Nout = (z == 9) ? 1024 : 512;
    if (z < 9 && blockIdx.x >= 16) return;
    const float* W; int slot;
    switch (z){
        case 0: W = v_w; slot = 0; break;
        case 1: W = gin_w1;               slot = 1; break;
        case 2: W = gin_w2;               slot = 2; break;
        case 3: W = gin_w1 + 262144;      slot = 3; break;
        case 4: W = gin_w2 + 262144;      slot = 4; break;
        case 5: W = gin_w1 + 524288;      slot = 5; break;
        case 6: W = gin_w2 + 524288;      slot = 6; break;
        case 7: W = se_w;  slot = 7; break;
        case 8: W = out_w; slot = 10; break;
        default: W = qk_w; slot = 8; break;
    }
    u16* Wh = wtsh + SLOT*slot;
    u16* Wl = wtsl + SLOT*slot;
    __shared__ float T[32][33];
    int nb = blockIdx.x*32, kb = blockIdx.y*32;
    int ln = threadIdx.x & 31, lk = threadIdx.x >> 5;
    #pragma unroll
    for (int i = 0; i < 4; i++)
        T[lk + 8*i][ln] = W[(size_t)(kb + lk + 8*i)*Nout + nb + ln];
    __syncthreads();
    #pragma unroll
    for (int i = 0; i < 4; i++){
        float val = T[ln][lk + 8*i];
        u16 h = tbf(val);
        size_t idx = (size_t)(nb + lk + 8*i)*512 + kb + ln;
        Wh[idx] = h;
        Wl[idx] = tbf(val - bf2f(h));
    }
}

// ---------------- fold: Wbig^T split = (diag(scale) @ M1)^T ----------------
// M1 f32 [512(k)][1024(n)]; out Wh/Wl [n][k] split bf16.
__global__ __launch_bounds__(256) void fold_transpose(const float* __restrict__ M1,
        const float* __restrict__ sc, u16* __restrict__ Wh, u16* __restrict__ Wl){
    __shared__ float T[32][33];
    int nb = blockIdx.x*32, kb = blockIdx.y*32;
    int ln = threadIdx.x & 31, lk = threadIdx.x >> 5;
    #pragma unroll
    for (int i = 0; i < 4; i++){
        int k = kb + lk + 8*i;
        T[lk + 8*i][ln] = M1[(size_t)k*1024 + nb + ln] * sc[k];
    }
    __syncthreads();
    #pragma unroll
    for (int i = 0; i < 4; i++){
        float val = T[ln][lk + 8*i];
        u16 h = tbf(val);
        size_t idx = (size_t)(nb + lk + 8*i)*512 + kb + ln;
        Wh[idx] = h;
        Wl[idx] = tbf(val - bf2f(h));
    }
}

// bbig[n] = sum_k shift[k]*M1[k][n] + se_b[k]*qk_w[k][n]  + qk_b[n]
__global__ void bias_fold(const float* __restrict__ M1, const float* __restrict__ sc,
        const float* __restrict__ se_b, const float* __restrict__ qk_w,
        const float* __restrict__ qk_b, float* __restrict__ bbig){
    int n = blockIdx.x*256 + threadIdx.x;
    if (n >= 1024) return;
    float acc = qk_b[n];
    for (int k = 0; k < 512; k++)
        acc += sc[512+k]*M1[(size_t)k*1024 + n] + se_b[k]*qk_w[(size_t)k*1024 + n];
    bbig[n] = acc;
}

// ---------------- split-bf16 MFMA GEMM (round-10-proven) ----------------
template<int ACT, int EPI>
__global__ __launch_bounds__(256) void gemm_ps(const u16* __restrict__ Ahg,
        const u16* __restrict__ Alg,
        const u16* __restrict__ Wth, const u16* __restrict__ Wtl,
        const float* __restrict__ bias,
        void* __restrict__ C0, void* __restrict__ C1, int K, int Nout){
    __shared__ __align__(16) u16 Ah[128][64];
    __shared__ __align__(16) u16 Al[128][64];
    __shared__ __align__(16) u16 Bh[128][64];
    __shared__ __align__(16) u16 Bl[128][64];
    int tid = threadIdx.x;
    int gx = gridDim.x;
    int nwg = gx * gridDim.y;
    int orig = blockIdx.x + gx*blockIdx.y;
    int q8 = nwg >> 3, r8 = nwg & 7;
    int xcd = orig & 7, pos = orig >> 3;
    int wg = (xcd < r8 ? xcd*(q8+1) : r8*(q8+1) + (xcd - r8)*q8) + pos;
    int rowBase = (wg / gx) * 128, colBase = (wg % gx) * 128;
    int w = tid >> 6, l = tid & 63, lg = l >> 4, lm = l & 15;
    int wr = w >> 1, wc = w & 1;
    f32x4 acc[4][4] = {};
    const u16* Ahp = Ahg + (size_t)rowBase*K;
    const u16* Alp = Alg + (size_t)rowBase*K;
    const u16* Wph = Wth + (size_t)colBase*K;
    const u16* Wpl = Wtl + (size_t)colBase*K;
    int srow[4], scol[4];
    #pragma unroll
    for (int c = 0; c < 4; c++){
        int slot = c*256 + tid;
        srow[c] = slot >> 3;
        scol[c] = ((slot & 7) ^ (srow[c] & 7)) * 8;
    }
    for (int k0 = 0; k0 < K; k0 += 64){
        #pragma unroll
        for (int c = 0; c < 4; c++){
            int slot = c*256 + tid;
            size_t so = (size_t)srow[c]*K + k0 + scol[c];
            GLOAD_LDS16(Ahp + so, &Ah[0][0] + slot*8);
            GLOAD_LDS16(Alp + so, &Al[0][0] + slot*8);
            GLOAD_LDS16(Wph + so, &Bh[0][0] + slot*8);
            GLOAD_LDS16(Wpl + so, &Bl[0][0] + slot*8);
        }
        __syncthreads();
        #pragma unroll
        for (int ks = 0; ks < 2; ks++){
            int scg = ((ks*4 + lg) ^ (lm & 7)) * 8;
            short8 ah[4], al[4], bh[4], bl[4];
            #pragma unroll
            for (int mf = 0; mf < 4; mf++){
                ah[mf] = *(const short8*)&Ah[wr*64 + mf*16 + lm][scg];
                al[mf] = *(const short8*)&Al[wr*64 + mf*16 + lm][scg];
            }
            #pragma unroll
            for (int nf = 0; nf < 4; nf++){
                bh[nf] = *(const short8*)&Bh[wc*64 + nf*16 + lm][scg];
                bl[nf] = *(const short8*)&Bl[wc*64 + nf*16 + lm][scg];
            }
            __builtin_amdgcn_s_setprio(1);
            #pragma unroll
            for (int mf = 0; mf < 4; mf++)
                #pragma unroll
                for (int nf = 0; nf < 4; nf++){
                    acc[mf][nf] = __builtin_amdgcn_mfma_f32_16x16x32_bf16(ah[mf], bh[nf], acc[mf][nf], 0, 0, 0);
                    acc[mf][nf] = __builtin_amdgcn_mfma_f32_16x16x32_bf16(al[mf], bh[nf], acc[mf][nf], 0, 0, 0);
                    acc[mf][nf] = __builtin_amdgcn_mfma_f32_16x16x32_bf16(ah[mf], bl[nf], acc[mf][nf], 0, 0, 0);
                }
            __builtin_amdgcn_s_setprio(0);
        }
        __syncthreads();
    }
    #pragma unroll
    for (int nf = 0; nf < 4; nf++){
        int col = colBase + wc*64 + nf*16 + lm;
        float bv = bias[col];
        #pragma unroll
        for (int mf = 0; mf < 4; mf++){
            int row = rowBase + wr*64 + mf*16 + lg*4;
            #pragma unroll
            for (int j = 0; j < 4; j++){
                float o = acc[mf][nf][j] + bv;
                if (ACT) o = fmaxf(o, 0.f);
                size_t idx = (size_t)(row + j)*Nout + col;
                if (EPI == 0){
                    ((float*)C0)[idx] = o;
                } else if (EPI == 1){
                    u16 hh = tbf(o);
                    ((u16*)C0)[idx] = hh;
                    ((u16*)C1)[idx] = tbf(o - bf2f(hh));
                } else {
                    ((u16*)C0)[idx] = f2bf(o);
                }
            }
        }
    }
}

// ---------------- BatchNorm stats ----------------
__global__ __launch_bounds__(256) void bn_stats_kernel(const u16* __restrict__ Ah,
        const u16* __restrict__ Al, float* __restrict__ sums, int n){
    int c = threadIdx.x;
    int r0 = blockIdx.x*128, r1 = min(n, r0+128);
    float s0=0.f, s1=0.f, q0=0.f, q1=0.f;
    for (int r = r0; r < r1; r++){
        float v0 = bf2f(Ah[(size_t)r*D + c])       + bf2f(Al[(size_t)r*D + c]);
        float v1 = bf2f(Ah[(size_t)r*D + 256 + c]) + bf2f(Al[(size_t)r*D + 256 + c]);
        s0 += v0; q0 += v0*v0; s1 += v1; q1 += v1*v1;
    }
    atomicAdd(&sums[c], s0);
    atomicAdd(&sums[c+256], s1);
    atomicAdd(&sums[512+c], q0);
    atomicAdd(&sums[512+c+256], q1);
}

__global__ void bn_final_kernel(const float* __restrict__ sums, const float* __restrict__ gamma,
        const float* __restrict__ beta, float* __restrict__ sc, int n){
    int c = threadIdx.x;
    float mean = sums[c] / (float)n;
    float var = sums[512+c] / (float)n - mean*mean;
    float r = rsqrtf(var + 1e-5f);
    float scale = r * gamma[c];
    sc[c] = scale;
    sc[512+c] = beta[c] - mean*scale;
}

// ---------------- MFMA ragged masked flash attention, 128-row q-blocks ----------------
#define ATS 72
__global__ __launch_bounds__(512) void attn_mfma_kernel(const u16* __restrict__ qkH,
        const u16* __restrict__ qkL, const u16* __restrict__ vbf,
        const u64* __restrict__ maskbits,
        const int* __restrict__ ptr, u16* __restrict__ oh, u16* __restrict__ ol, int N){
    __shared__ u16 Kh[64][ATS];
    __shared__ u16 Kl[64][ATS];
    __shared__ u16 Vt[64][ATS];
    __shared__ u16 Pl[8][16][ATS];
    int b = blockIdx.z, h = blockIdx.y;
    int base = ptr[b], size = ptr[b+1] - base;
    int q0 = blockIdx.x * 128;
    if (q0 >= size) return;
    int tid = threadIdx.x, w = tid >> 6, l = tid & 63;
    int lg = l >> 4, lm = l & 15;
    short8 qh[2], ql[2];
    {
        int qrow = q0 + w*16 + lm;
        int qr = (qrow < size) ? qrow : 0;
        const u16* qph = qkH + (size_t)(base + qr)*1024 + 512 + h*64;
        const u16* qpl = qkL + (size_t)(base + qr)*1024 + 512 + h*64;
        #pragma unroll
        for (int ks = 0; ks < 2; ks++){
            short8 th = *(const short8*)(qph + ks*32 + lg*8);
            short8 tl = *(const short8*)(qpl + ks*32 + lg*8);
            if (qrow >= size){ th = short8{0,0,0,0,0,0,0,0}; tl = short8{0,0,0,0,0,0,0,0}; }
            qh[ks] = th; ql[ks] = tl;
        }
    }
    f32x4 acco[4] = {};
    float mrow[4], lrow[4];
    #pragma unroll
    for (int j = 0; j < 4; j++){ mrow[j] = -INFINITY; lrow[j] = 0.f; }
    int nt = (size + 63) >> 6;
    for (int t = 0; t < nt; t++){
        int j0 = t*64;
        __syncthreads();
        {   // 512 threads: key jj = tid&63, dims db = (tid>>6)*8 .. +8
            int jj = tid & 63, db = (tid >> 6)*8;
            int key = j0 + jj;
            bool ok = key < size;
            size_t node = (size_t)(base + (ok ? key : 0));
            const u16* khp = qkH + node*1024 + h*64 + db;
            const u16* klp = qkL + node*1024 + h*64 + db;
            const u16* vp  = vbf + node*512  + h*64 + db;
            ushort8 z = {0,0,0,0,0,0,0,0};
            ushort8 kh0 = ok ? *(const ushort8*)(khp) : z;
            ushort8 kl0 = ok ? *(const ushort8*)(klp) : z;
            ushort8 v0  = ok ? *(const ushort8*)(vp)  : z;
            *(ushort8*)&Kh[jj][db] = kh0;
            *(ushort8*)&Kl[jj][db] = kl0;
            #pragma unroll
            for (int i = 0; i < 8; i++) Vt[db + i][jj] = v0[i];
        }
        __syncthreads();
        f32x4 sc[4] = {};
        __builtin_amdgcn_s_setprio(1);
        #pragma unroll
        for (int nf = 0; nf < 4; nf++)
            #pragma unroll
            for (int ks = 0; ks < 2; ks++){
                short8 kh = *(const short8*)&Kh[nf*16 + lm][ks*32 + lg*8];
                short8 kl = *(const short8*)&Kl[nf*16 + lm][ks*32 + lg*8];
                sc[nf] = __builtin_amdgcn_mfma_f32_16x16x32_bf16(qh[ks], kh, sc[nf], 0, 0, 0);
                sc[nf] = __builtin_amdgcn_mfma_f32_16x16x32_bf16(ql[ks], kh, sc[nf], 0, 0, 0);
                sc[nf] = __builtin_amdgcn_mfma_f32_16x16x32_bf16(qh[ks], kl, sc[nf], 0, 0, 0);
            }
        __builtin_amdgcn_s_setprio(0);
        u64 mb[4];
        #pragma unroll
        for (int j = 0; j < 4; j++)
            mb[j] = maskbits[((size_t)b*LMAX + (q0 + w*16 + lg*4 + j))*8 + t];
        float mx[4], alpha[4];
        #pragma unroll
        for (int j = 0; j < 4; j++){
            float s0 = -INFINITY;
            #pragma unroll
            for (int nf = 0; nf < 4; nf++){
                int key = j0 + nf*16 + lm;
                float s = sc[nf][j] * 0.125f;
                bool msk = (key >= size) || ((mb[j] >> (nf*16 + lm)) & 1);
                s = msk ? -INFINITY : s;
                sc[nf][j] = s;
                s0 = fmaxf(s0, s);
            }
            #pragma unroll
            for (int off = 1; off < 16; off <<= 1) s0 = fmaxf(s0, __shfl_xor(s0, off));
            mx[j] = s0;
        }
        #pragma unroll
        for (int j = 0; j < 4; j++){
            if (mx[j] == -INFINITY){ alpha[j] = 1.f; }
            else {
                float mn = fmaxf(mrow[j], mx[j]);
                alpha[j] = __expf(mrow[j] - mn);
                mrow[j] = mn;
            }
        }
        float ps[4] = {0.f, 0.f, 0.f, 0.f};
        #pragma unroll
        for (int nf = 0; nf < 4; nf++)
            #pragma unroll
            for (int j = 0; j < 4; j++){
                float p = (mx[j] == -INFINITY) ? 0.f : __expf(sc[nf][j] - mrow[j]);
                ps[j] += p;
                Pl[w][lg*4 + j][nf*16 + lm] = tbf(p);
            }
        #pragma unroll
        for (int j = 0; j < 4; j++){
            float s = ps[j];
            #pragma unroll
            for (int off = 1; off < 16; off <<= 1) s += __shfl_xor(s, off);
            lrow[j] = lrow[j]*alpha[j] + s;
        }
        #pragma unroll
        for (int df = 0; df < 4; df++)
            #pragma unroll
            for (int j = 0; j < 4; j++) acco[df][j] *= alpha[j];
        __builtin_amdgcn_s_setprio(1);
        #pragma unroll
        for (int ks = 0; ks < 2; ks++){
            short8 pf = *(const short8*)&Pl[w][lm][ks*32 + lg*8];
            #pragma unroll
            for (int df = 0; df < 4; df++){
                short8 vf = *(const short8*)&Vt[df*16 + lm][ks*32 + lg*8];
                acco[df] = __builtin_amdgcn_mfma_f32_16x16x32_bf16(pf, vf, acco[df], 0, 0, 0);
            }
        }
        __builtin_amdgcn_s_setprio(0);
    }
    #pragma unroll
    for (int j = 0; j < 4; j++){
        int r = q0 + w*16 + lg*4 + j;
        if (r < size){
            float inv = 1.f / lrow[j];
            #pragma unroll
            for (int df = 0; df < 4; df++){
                float o = acco[df][j] * inv;
                size_t idx = (size_t)(base + r)*D + h*64 + df*16 + lm;
                u16 hh = tbf(o);
                oh[idx] = hh;
                ol[idx] = tbf(o - bf2f(hh));
            }
        }
    }
}

extern "C" void kernel_launch(void* const* d_in, const int* in_sizes, int n_in,
                              void* d_out, int out_size, void* d_ws, size_t ws_size,
                              hipStream_t stream){
    const float* x        = (const float*)d_in[0];
    const int*   ei_raw   = (const int*)d_in[1];
    const unsigned char* mask_raw = (const unsigned char*)d_in[2];
    const int*   ptr_raw  = (const int*)d_in[3];
    const float* gin_w1   = (const float*)d_in[4];
    const float* gin_b1   = (const float*)d_in[5];
    const float* gin_w2   = (const float*)d_in[6];
    const float* gin_b2   = (const float*)d_in[7];
    const float* bn_gamma = (const float*)d_in[8];
    const float* bn_beta  = (const float*)d_in[9];
    const float* se_w     = (const float*)d_in[10];
    const float* se_b     = (const float*)d_in[11];
    const float* qk_w     = (const float*)d_in[12];
    const float* qk_b     = (const float*)d_in[13];
    const float* v_w      = (const float*)d_in[14];
    const float* v_b      = (const float*)d_in[15];
    const float* out_w    = (const float*)d_in[16];
    const float* out_b    = (const float*)d_in[17];

    const int N  = in_sizes[0] / D;       // 12160
    const int E  = in_sizes[1] / 2;       // 97280
    const int B  = in_sizes[3] - 1;       // 32
    const int Mn = in_sizes[2];           // B*512*512

    char* ws = (char*)d_ws;
    char* p = ws;
    auto alloc = [&](size_t bytes) -> char* {
        char* q = p; p += (bytes + 255) & ~(size_t)255; return q;
    };
    size_t PLANE = (size_t)N * D * sizeof(u16);
    u16* pairX = (u16*)alloc(2*PLANE);
    u16* pairG = (u16*)alloc(2*PLANE);
    u16* pairT = (u16*)alloc(2*PLANE);
    u16* pairH = (u16*)alloc(2*PLANE);
    u16* v_bf  = (u16*)alloc(PLANE);
    u16* Xh = pairX, *Xl = pairX + (size_t)N*D;
    u16* Gh = pairG, *Gl = pairG + (size_t)N*D;
    u16* Th = pairT, *Tl = pairT + (size_t)N*D;
    u16* Hh = pairH, *Hl = pairH + (size_t)N*D;
    float* sums   = (float*)alloc(1024*sizeof(float));
    float* sc     = (float*)alloc(1024*sizeof(float));
    int*   flags  = (int*)alloc(16*sizeof(int));
    int*   deg    = (int*)alloc((size_t)N*sizeof(int));
    int*   offs   = (int*)alloc((size_t)(N+1)*sizeof(int));
    int*   cursor = (int*)alloc((size_t)N*sizeof(int));
    int*   in_src = (int*)alloc((size_t)E*sizeof(int));
    int*   ptr32  = (int*)alloc(64*sizeof(int));
    int*   ei32   = (int*)alloc((size_t)2*E*sizeof(int));
    u64*   mbits  = (u64*)alloc((size_t)(Mn/64)*sizeof(u64));
    u16*   wtsh   = (u16*)alloc((size_t)2883584*sizeof(u16));
    u16*   wtsl   = (u16*)alloc((size_t)2883584*sizeof(u16));
    // fusion scratch
    u16*   sewh   = (u16*)alloc((size_t)D*D*sizeof(u16));
    u16*   sewl   = (u16*)alloc((size_t)D*D*sizeof(u16));
    float* M1     = (float*)alloc((size_t)D*1024*sizeof(float));
    u16*   wbig_h = (u16*)alloc((size_t)1024*D*sizeof(u16));
    u16*   wbig_l = (u16*)alloc((size_t)1024*D*sizeof(u16));
    float* bbig   = (float*)alloc(1024*sizeof(float));
    float* zbias  = (float*)alloc(1024*sizeof(float));
    const size_t SLOT = 262144;
    u16 *wh_v = wtsh, *wl_v = wtsl;
    u16 *wh_g[6], *wl_g[6];
    for (int i = 0; i < 6; i++){ wh_g[i] = wtsh + SLOT*(1+i); wl_g[i] = wtsl + SLOT*(1+i); }
    u16 *wh_qk  = wtsh + SLOT*8,  *wl_qk  = wtsl + SLOT*8;
    u16 *wh_out = wtsh + SLOT*10, *wl_out = wtsl + SLOT*10;

    // --- dtype probe + normalization ---
    probe_kernel<<<1, 64, 0, stream>>>(ptr_raw, mask_raw, flags);
    conv_int_kernel<<<1, 64, 0, stream>>>(ptr_raw, ptr32, flags, B + 1);
    conv_int_kernel<<<(2*E + 255)/256, 256, 0, stream>>>(ei_raw, ei32, flags, 2*E);
    maskbits_kernel<<<(Mn/64 + 255)/256, 256, 0, stream>>>(mask_raw, mbits, flags, Mn/64);

    // --- CSR inversion ---
    hipMemsetAsync(deg, 0, (size_t)N*sizeof(int), stream);
    hipMemsetAsync(cursor, 0, (size_t)N*sizeof(int), stream);
    hipMemsetAsync(zbias, 0, 1024*sizeof(float), stream);
    count_kernel<<<(E+255)/256, 256, 0, stream>>>(ei32, deg, E, N);
    scan_kernel<<<1, 1024, 0, stream>>>(deg, offs, N);
    fill_kernel<<<(E+255)/256, 256, 0, stream>>>(ei32, offs, cursor, in_src, E, N);

    // --- weight transposes + splits ---
    transpose_all<<<dim3(32,16,10), 256, 0, stream>>>(v_w, gin_w1, gin_w2, se_w, out_w, qk_w, wtsh, wtsl);
    split_kernel<<<(N*D/4 + 255)/256, 256, 0, stream>>>(x, Xh, Xl, N*D/4);
    split_kernel<<<(D*D/4 + 255)/256, 256, 0, stream>>>(se_w, sewh, sewl, D*D/4);

    // M1 = se_w @ qk_w  (f32, [512][1024]) — small fused-weight GEMM
    gemm_ps<0,0><<<dim3(8,4), 256, 0, stream>>>(sewh, sewl, wh_qk, wl_qk, zbias, M1, nullptr, D, 2*D);

    dim3 g512(4, N/128), g1024(8, N/128);

    // v = x @ v_w + v_b  -> plain bf16
    gemm_ps<0,2><<<g512, 256, 0, stream>>>(Xh, Xl, wh_v, wl_v, v_b, v_bf, nullptr, D, D);

    // GIN layers
    for (int i = 0; i < NGIN; i++){
        const u16* sh = (i == 0) ? Xh : Hh;
        const u16* sl = (i == 0) ? Xl : Hl;
        gather_kernel<<<(N+1)/2, 256, 0, stream>>>(sh, sl, offs, in_src, Gh, Gl, N);
        gemm_ps<1,1><<<g512, 256, 0, stream>>>(Gh, Gl, wh_g[2*i],   wl_g[2*i],   gin_b1 + (size_t)i*D, Th, Tl, D, D);
        gemm_ps<1,1><<<g512, 256, 0, stream>>>(Th, Tl, wh_g[2*i+1], wl_g[2*i+1], gin_b2 + (size_t)i*D, Hh, Hl, D, D);
    }

    // BatchNorm stats -> sc (scale, shift)
    hipMemsetAsync(sums, 0, 1024*sizeof(float), stream);
    bn_stats_kernel<<<(N+127)/128, 256, 0, stream>>>(Hh, Hl, sums, N);
    bn_final_kernel<<<1, 512, 0, stream>>>(sums, bn_gamma, bn_beta, sc, N);

    // fold BN + se into the qk weight:  Wbig = diag(scale)@M1 (transposed split), bbig = shift@M1 + se_b@qk_w + qk_b
    fold_transpose<<<dim3(32,16), 256, 0, stream>>>(M1, sc, wbig_h, wbig_l);
    bias_fold<<<4, 256, 0, stream>>>(M1, sc, se_b, qk_w, qk_b, bbig);

    // qk = gin_out @ Wbig + bbig : pairH -> hi plane = pairX (N x 1024), lo plane = pairG
    gemm_ps<0,1><<<g1024, 256, 0, stream>>>(Hh, Hl, wbig_h, wbig_l, bbig, pairX, pairG, D, 2*D);

    // attention: split qk + bf16 v -> split output in pairT (128-row q-blocks, 8 waves)
    attn_mfma_kernel<<<dim3(LMAX/128, NHEAD, B), 512, 0, stream>>>(pairX, pairG, v_bf, mbits, ptr32, Th, Tl, N);

    // out = attn_out @ out_w + out_b -> f32 d_out
    gemm_ps<0,0><<<g512, 256, 0, stream>>>(Th, Tl, wh_out, wl_out, out_b, (float*)d_out, nullptr, D, D);
}